// Round 8
// baseline (1139.015 us; speedup 1.0000x reference)
//
#include <hip/hip_runtime.h>

// Problem constants (fixed by setup_inputs: T=8, N=2048, D=256)
#define T_ALL 8
#define T1    7
#define NPTS  2048
#define DD    256
#define NPB   16                     // 128-col blocks per frame
#define MARGIN_THR 6.0e-3f           // 6x the OBSERVED 1e-3 split-bf16 error (R7)
#define RCHUNK 8                     // recheck col-chunks per row (256 cols each)

// ws layout (floats)
#define O_ND    0                                  // fp32 normalized [16384][256]
#define O_HI    (O_ND + T_ALL*NPTS*DD)             // bf16 hi, frag layout (shorts)
#define O_LO    (O_HI + T_ALL*NPTS*DD/2)
#define O_PV1   (O_LO + T_ALL*NPTS*DD/2)           // per (row, colblock) top1
#define O_PI1   (O_PV1 + T1*NPTS*NPB)
#define O_PV2   (O_PI1 + T1*NPTS*NPB)              // per (row, colblock) top2
#define O_BEST  (O_PV2 + T1*NPTS*NPB)              // u64 [14336]
#define O_WL    (O_BEST + T1*NPTS*2)               // int worklist [14336]
#define O_CNT   (O_WL + T1*NPTS)                   // int counter

typedef __attribute__((ext_vector_type(8))) short short8v;   // 8 bf16 (4 VGPR)
typedef __attribute__((ext_vector_type(4))) float float4v;   // MFMA acc

__device__ __forceinline__ unsigned short f2bf(float x) {    // RNE f32->bf16
    unsigned u = __float_as_uint(x);
    return (unsigned short)((u + 0x7FFFu + ((u >> 16) & 1u)) >> 16);
}
__device__ __forceinline__ float bf2f(unsigned short h) {
    return __uint_as_float(((unsigned)h) << 16);
}
// monotone pack: larger value wins; equal value -> smaller idx wins
__device__ __forceinline__ unsigned long long packVI(float v, int idx) {
    unsigned int b = __float_as_uint(v);
    b = (b & 0x80000000u) ? ~b : (b | 0x80000000u);
    return ((unsigned long long)b << 32) | (unsigned int)(NPTS - 1 - idx);
}

// ---------------------------------------------------------------------------
// Kernel 1: normalize rows; emit fp32 nd + bf16 hi/lo in MFMA-frag layout.
// Frag layout per 16-row group: [kstep 0..7][lane 0..63][e 0..7] shorts where
// lane=(row&15)+16*((k>>2)&3), e=4*((k>>4)&1)+(k&3), k=kstep*32+kk. A and B
// use the SAME map, so any HW k-permutation cancels in the dot product.
// Also zeroes the recheck worklist counter.
// ---------------------------------------------------------------------------
__global__ __launch_bounds__(256) void prep_kernel(const float* __restrict__ desc,
                                                   float* __restrict__ nd,
                                                   ushort* __restrict__ ghi,
                                                   ushort* __restrict__ glo,
                                                   int* __restrict__ cnt) {
    int gid  = blockIdx.x * 256 + threadIdx.x;
    if (gid == 0) *cnt = 0;
    int row  = gid >> 6;
    int lane = gid & 63;
    float4 v = reinterpret_cast<const float4*>(desc)[(size_t)row * (DD / 4) + lane];
    float s = v.x * v.x + v.y * v.y + v.z * v.z + v.w * v.w;
#pragma unroll
    for (int off = 32; off >= 1; off >>= 1) s += __shfl_xor(s, off, 64);
    float n = fmaxf(sqrtf(s), 1e-8f);
    float4 o = make_float4(v.x / n, v.y / n, v.z / n, v.w / n);
    reinterpret_cast<float4*>(nd)[(size_t)row * (DD / 4) + lane] = o;

    ushort4 h, l;
    h.x = f2bf(o.x); l.x = f2bf(o.x - bf2f(h.x));
    h.y = f2bf(o.y); l.y = f2bf(o.y - bf2f(h.y));
    h.z = f2bf(o.z); l.z = f2bf(o.z - bf2f(h.z));
    h.w = f2bf(o.w); l.w = f2bf(o.w - bf2f(h.w));
    // k = 4*lane + j: kstep=lane>>3, sub=lane&3, eb=(lane>>2)&1, e=4*eb+j
    size_t base = ((size_t)(row >> 4) * 8 + (lane >> 3)) * 512
                + (size_t)((row & 15) + 16 * (lane & 3)) * 8 + 4 * ((lane >> 2) & 1);
    *reinterpret_cast<ushort4*>(ghi + base) = h;
    *reinterpret_cast<ushort4*>(glo + base) = l;
}

// ---------------------------------------------------------------------------
// Kernel 2: MFMA match. Block = 256 thr (4 waves), tile 128 rows x 128 cols,
// K_eff = 768 (3 passes: hi*hi, hi*lo, lo*hi), BK=32 per round, 24 rounds.
// Per wave: 64x64 quadrant = 4x4 MFMA(16x16x32) frags. Epilogue: per-row
// (top1,idx,top2) -> per-(row,colblock) partials.
// ---------------------------------------------------------------------------
__global__ __launch_bounds__(256) void match_kernel(const ushort* __restrict__ ghi,
                                                    const ushort* __restrict__ glo,
                                                    float* __restrict__ pV1,
                                                    int* __restrict__ pI1,
                                                    float* __restrict__ pV2) {
    __shared__ __align__(16) ushort sAB[8192];     // sA 8KB | sB 8KB
    const int bid = blockIdx.x;                    // ((t*16)+rb)*16 + cb
    const int cb  = bid & 15;
    const int rb  = (bid >> 4) & 15;
    const int t   = bid >> 8;
    const int tid = threadIdx.x;
    const int w   = tid >> 6;                      // wave 0..3
    const int l   = tid & 63;
    const int wr  = w >> 1;                        // row quadrant
    const int wc  = w & 1;                         // col quadrant

    // staging role: threads 0..127 -> A, 128..255 -> B; 64B per thread/round
    const int half = tid >> 7;
    const int g    = (tid & 127) >> 4;             // row/col group 0..7
    const int c    = tid & 15;                     // 64B chunk
    const int rg   = half ? ((t + 1) * 128 + cb * 8 + g)
                          : (t * 128 + rb * 8 + g);

    uint4 pr0, pr1, pr2, pr3;
    auto issue = [&](int rd) {
        bool useLo = half ? (rd >= 8 && rd < 16) : (rd >= 16);
        const ushort* bp = useLo ? glo : ghi;
        const ushort* sp = bp + (((size_t)rg * 8 + (rd & 7)) << 9) + (c << 5);
        const uint4* u = reinterpret_cast<const uint4*>(sp);
        pr0 = u[0]; pr1 = u[1]; pr2 = u[2]; pr3 = u[3];
    };
    auto stage = [&]() {
        ushort* d = sAB + (half ? 4096 : 0) + (g << 9) + (c << 5);
        uint4* u = reinterpret_cast<uint4*>(d);
        u[0] = pr0; u[1] = pr1; u[2] = pr2; u[3] = pr3;
    };

    float4v acc[4][4];
#pragma unroll
    for (int fa = 0; fa < 4; ++fa)
#pragma unroll
        for (int fb = 0; fb < 4; ++fb) acc[fa][fb] = (float4v){0.f, 0.f, 0.f, 0.f};

    issue(0);
#pragma unroll 1
    for (int rd = 0; rd < 24; ++rd) {
        stage();
        __syncthreads();                           // tiles ready
        if (rd < 23) issue(rd + 1);                // loads fly under MFMA
        short8v af[4], bfr[4];
#pragma unroll
        for (int f = 0; f < 4; ++f) {
            af[f]  = *reinterpret_cast<const short8v*>(sAB + ((wr * 4 + f) << 9) + (l << 3));
            bfr[f] = *reinterpret_cast<const short8v*>(sAB + 4096 + ((wc * 4 + f) << 9) + (l << 3));
        }
#pragma unroll
        for (int fa = 0; fa < 4; ++fa)
#pragma unroll
            for (int fb = 0; fb < 4; ++fb)
                acc[fa][fb] = __builtin_amdgcn_mfma_f32_16x16x32_bf16(
                    af[fa], bfr[fb], acc[fa][fb], 0, 0, 0);
        __syncthreads();                           // reads done before re-stage
    }

    // ---- epilogue: D row = wr*64+fa*16+4*(l>>4)+r, col = wc*64+fb*16+(l&15)
    float* exV1 = (float*)sAB;                     // [2][128]
    int*   exI1 = (int*)sAB + 256;
    float* exV2 = (float*)sAB + 512;
    __syncthreads();
#pragma unroll
    for (int fa = 0; fa < 4; ++fa) {
#pragma unroll
        for (int r = 0; r < 4; ++r) {
            float v1 = -3.0e38f, v2 = -3.0e38f; int i1 = 0;
#pragma unroll
            for (int fb = 0; fb < 4; ++fb) {
                float x  = acc[fa][fb][r];
                int  col = cb * 128 + wc * 64 + fb * 16 + (l & 15);
                if (x > v1) { v2 = v1; v1 = x; i1 = col; }
                else        { v2 = fmaxf(v2, x); }
            }
#pragma unroll
            for (int m = 1; m <= 8; m <<= 1) {     // 16-lane butterfly
                float ov1 = __shfl_xor(v1, m);
                int   oi1 = __shfl_xor(i1, m);
                float ov2 = __shfl_xor(v2, m);
                bool take = (ov1 > v1) || (ov1 == v1 && oi1 < i1);
                float nv2 = take ? fmaxf(ov2, v1) : fmaxf(v2, ov1);
                v1 = take ? ov1 : v1;  i1 = take ? oi1 : i1;  v2 = nv2;
            }
            if ((l & 15) == 0) {
                int rloc = wr * 64 + fa * 16 + (l >> 4) * 4 + r;
                exV1[wc * 128 + rloc] = v1;
                exI1[wc * 128 + rloc] = i1;
                exV2[wc * 128 + rloc] = v2;
            }
        }
    }
    __syncthreads();
    if (tid < 128) {
        float v1 = exV1[tid];       int i1 = exI1[tid];       float v2 = exV2[tid];
        float b1 = exV1[128 + tid]; int bi = exI1[128 + tid]; float b2 = exV2[128 + tid];
        bool take = (b1 > v1) || (b1 == v1 && bi < i1);
        float nv2 = take ? fmaxf(b2, v1) : fmaxf(v2, b1);
        if (take) { v1 = b1; i1 = bi; }
        int idx = (t * NPTS + rb * 128 + tid) * NPB + cb;
        pV1[idx] = v1; pI1[idx] = i1; pV2[idx] = nv2;
    }
}

// ---------------------------------------------------------------------------
// Kernel 3: exact global top-2 margin per row; near-ties go to the worklist,
// safe rows get their (approx) best committed directly.
// ---------------------------------------------------------------------------
__global__ __launch_bounds__(256) void margin_kernel(const float* __restrict__ pV1,
                                                     const int* __restrict__ pI1,
                                                     const float* __restrict__ pV2,
                                                     unsigned long long* __restrict__ best,
                                                     int* __restrict__ wl,
                                                     int* __restrict__ cnt) {
    int r = blockIdx.x * 256 + threadIdx.x;        // 0..14335
    float v1 = -3.0e38f, v2 = -3.0e38f; int i1 = 0;
#pragma unroll
    for (int cbk = 0; cbk < NPB; ++cbk) {          // ascending -> first-occurrence
        int idx = r * NPB + cbk;
        float a1 = pV1[idx]; int ai = pI1[idx]; float a2 = pV2[idx];
        if (a1 > v1) { v2 = fmaxf(v1, a2); v1 = a1; i1 = ai; }
        else         { v2 = fmaxf(v2, a1); }
    }
    if (v1 - v2 < MARGIN_THR) {
        best[r] = 0ull;                            // below any real packed value
        wl[atomicAdd(cnt, 1)] = r;
    } else {
        best[r] = packVI(v1, i1);
    }
}

// ---------------------------------------------------------------------------
// Kernel 4: exact fp32 rescore of flagged rows, fine-grained: work item =
// (flagged row, 256-col chunk); one col per thread; wave butterfly top-1;
// packed atomicMax merge (order-independent). Same ascending-k fmaf chain
// as R2-R6 (bitwise-matched reference).
// ---------------------------------------------------------------------------
__global__ __launch_bounds__(256) void recheck_kernel(const float* __restrict__ nd,
                                                      const int* __restrict__ wl,
                                                      const int* __restrict__ cnt,
                                                      unsigned long long* __restrict__ best) {
    __shared__ float sSrc[DD];
    const int nitems = (*cnt) * RCHUNK;
    const int tid = threadIdx.x;
#pragma unroll 1
    for (int item = blockIdx.x; item < nitems; item += gridDim.x) {
        const int r     = wl[item / RCHUNK];
        const int chunk = item % RCHUNK;
        const int t = r >> 11, row = r & (NPTS - 1);
        __syncthreads();                           // sSrc free
        if (tid < 64)
            reinterpret_cast<float4*>(sSrc)[tid] =
                reinterpret_cast<const float4*>(nd + ((size_t)(t * NPTS + row)) * DD)[tid];
        __syncthreads();
        const int col = chunk * 256 + tid;
        const float* dp = nd + ((size_t)((t + 1) * NPTS) + col) * DD;
        float a = 0.f;
#pragma unroll
        for (int k4 = 0; k4 < 64; ++k4) {          // sequential ascending k
            float4 s4 = reinterpret_cast<const float4*>(sSrc)[k4];
            float4 d4 = reinterpret_cast<const float4*>(dp)[k4];
            a = fmaf(s4.x, d4.x, a); a = fmaf(s4.y, d4.y, a);
            a = fmaf(s4.z, d4.z, a); a = fmaf(s4.w, d4.w, a);
        }
        float bv = a; int bi = col;
#pragma unroll
        for (int m = 1; m <= 32; m <<= 1) {        // 64-lane butterfly top-1
            float ov = __shfl_xor(bv, m);
            int   oi = __shfl_xor(bi, m);
            if (ov > bv || (ov == bv && oi < bi)) { bv = ov; bi = oi; }
        }
        if ((tid & 63) == 0)
            atomicMax(&best[r], packVI(bv, bi));
    }
}

// ---------------------------------------------------------------------------
// Kernel 5: unpack best[], gather matched points, write outputs.
// ---------------------------------------------------------------------------
__global__ __launch_bounds__(256) void final_kernel(const unsigned long long* __restrict__ best,
                                                    const float* __restrict__ pts,
                                                    float* __restrict__ out) {
    int r = blockIdx.x * 256 + threadIdx.x;
    int t = r >> 11;
    unsigned long long p = best[r];
    int idx = NPTS - 1 - (int)(p & 0xFFFFFFFFull);
    unsigned int b = (unsigned int)(p >> 32);
    b = (b & 0x80000000u) ? (b & 0x7FFFFFFFu) : ~b;
    out[(size_t)T1 * NPTS * 2 + r] = __uint_as_float(b);
    const float* q = pts + ((size_t)((t + 1) * NPTS) + idx) * 2;
    out[(size_t)r * 2 + 0] = q[0];
    out[(size_t)r * 2 + 1] = q[1];
}

// ---------------------------------------------------------------------------
extern "C" void kernel_launch(void* const* d_in, const int* in_sizes, int n_in,
                              void* d_out, int out_size, void* d_ws, size_t ws_size,
                              hipStream_t stream) {
    const float* desc = (const float*)d_in[0];     // [8, 2048, 256] fp32
    const float* pts  = (const float*)d_in[1];     // [8, 2048, 2]   fp32
    float* ws = (float*)d_ws;
    float* nd  = ws + O_ND;
    ushort* ghi = (ushort*)(ws + O_HI);
    ushort* glo = (ushort*)(ws + O_LO);
    float* pV1 = ws + O_PV1;
    int*   pI1 = (int*)(ws + O_PI1);
    float* pV2 = ws + O_PV2;
    unsigned long long* best = (unsigned long long*)(ws + O_BEST);
    int* wl  = (int*)(ws + O_WL);
    int* cnt = (int*)(ws + O_CNT);

    prep_kernel<<<(T_ALL * NPTS) / 4, 256, 0, stream>>>(desc, nd, ghi, glo, cnt);
    match_kernel<<<T1 * 16 * 16, 256, 0, stream>>>(ghi, glo, pV1, pI1, pV2);
    margin_kernel<<<(T1 * NPTS) / 256, 256, 0, stream>>>(pV1, pI1, pV2, best, wl, cnt);
    recheck_kernel<<<2048, 256, 0, stream>>>(nd, wl, cnt, best);
    final_kernel<<<(T1 * NPTS) / 256, 256, 0, stream>>>(best, pts, (float*)d_out);
}

// Round 9
// 273.886 us; speedup vs baseline: 4.1587x; 4.1587x over previous
//
#include <hip/hip_runtime.h>

// Problem constants (fixed by setup_inputs: T=8, N=2048, D=256)
#define T_ALL 8
#define T1    7
#define NPTS  2048
#define DD    256
#define NPB   16                     // 128-col blocks per frame
#define MARGIN_THR 5.0e-5f           // rigorous: quant+omitted-term margin err <= ~1.2e-5
#define RCHUNK 8                     // recheck col-chunks per row (256 cols each)

// ws layout (floats)
#define O_ND    0                                  // fp32 normalized [16384][256]
#define O_D2    (O_ND + T_ALL*NPTS*DD)             // i8 digit a (frag layout), 4MB
#define O_D1    (O_D2 + T_ALL*NPTS*DD/4)           // i8 digit b
#define O_D0    (O_D1 + T_ALL*NPTS*DD/4)           // i8 digit c
#define O_PV1   (O_D0 + T_ALL*NPTS*DD/4)           // per (row, colblock) top1
#define O_PI1   (O_PV1 + T1*NPTS*NPB)
#define O_PV2   (O_PI1 + T1*NPTS*NPB)              // per (row, colblock) top2
#define O_BEST  (O_PV2 + T1*NPTS*NPB)              // u64 [14336]
#define O_WL    (O_BEST + T1*NPTS*2)               // int worklist [14336]
#define O_CNT   (O_WL + T1*NPTS)                   // int counter

typedef __attribute__((ext_vector_type(4))) int   int4v;    // i8 MFMA A/B/C
typedef __attribute__((ext_vector_type(4))) float float4v;

// monotone pack: larger value wins; equal value -> smaller idx wins
__device__ __forceinline__ unsigned long long packVI(float v, int idx) {
    unsigned int b = __float_as_uint(v);
    b = (b & 0x80000000u) ? ~b : (b | 0x80000000u);
    return ((unsigned long long)b << 32) | (unsigned int)(NPTS - 1 - idx);
}

// ---------------------------------------------------------------------------
// Kernel 1: normalize rows -> nd (fp32); quantize q=round(x*2^21) into 7-bit
// digits a,b,c (q = a*2^14 + b*2^7 + c exactly, incl. negatives) stored i8 in
// MFMA-frag layout for 16x16x64: within a (rowgroup, 64k-slab) 1KB tile,
// byte = flane*16 + e, flane = (row&15) + 16*((k>>4)&3), e = k&15.
// A and B use the SAME map -> HW k-permutation cancels in the dot product.
// ---------------------------------------------------------------------------
__global__ __launch_bounds__(256) void prep_kernel(const float* __restrict__ desc,
                                                   float* __restrict__ nd,
                                                   char* __restrict__ d2,
                                                   char* __restrict__ d1,
                                                   char* __restrict__ d0,
                                                   int* __restrict__ cnt) {
    int gid  = blockIdx.x * 256 + threadIdx.x;
    if (gid == 0) *cnt = 0;
    int row  = gid >> 6;
    int lane = gid & 63;
    float4 v = reinterpret_cast<const float4*>(desc)[(size_t)row * (DD / 4) + lane];
    float s = v.x * v.x + v.y * v.y + v.z * v.z + v.w * v.w;
#pragma unroll
    for (int off = 32; off >= 1; off >>= 1) s += __shfl_xor(s, off, 64);
    float n = fmaxf(sqrtf(s), 1e-8f);
    float4 o = make_float4(v.x / n, v.y / n, v.z / n, v.w / n);
    reinterpret_cast<float4*>(nd)[(size_t)row * (DD / 4) + lane] = o;

    float xs[4] = {o.x, o.y, o.z, o.w};
    char a4[4], b4[4], c4[4];
#pragma unroll
    for (int j = 0; j < 4; ++j) {
        int q = (int)lrintf(xs[j] * 2097152.0f);          // 2^21
        q = min(max(q, -2097152), 2097151);
        a4[j] = (char)(q >> 14);                          // [-128,127]
        b4[j] = (char)((q >> 7) & 127);                   // [0,127]
        c4[j] = (char)(q & 127);                          // [0,127]
    }
    // k = 4*lane + j: slab=k>>6=lane>>4, (k>>4)&3=(lane>>2)&3, e=k&15=4*(lane&3)+j
    size_t base = ((size_t)(row >> 4) * 4 + (lane >> 4)) * 1024
                + (size_t)((row & 15) + 16 * ((lane >> 2) & 3)) * 16 + 4 * (lane & 3);
    *reinterpret_cast<char4*>(d2 + base) = *(char4*)a4;
    *reinterpret_cast<char4*>(d1 + base) = *(char4*)b4;
    *reinterpret_cast<char4*>(d0 + base) = *(char4*)c4;
}

// ---------------------------------------------------------------------------
// Kernel 2: i8 MFMA match, EXACT in i32 per epoch. Block = 256 thr (4 waves),
// tile 128x128; per wave 64x64 = 4x4 frags of 16x16x64. 24 rounds = 6 passes
// x 4 k-slabs: (a,a) | (a,b),(b,a) | (b,b),(a,c),(c,a); i32 epoch sums are
// flushed to fp32 with 2^-14 / 2^-21 / 2^-28.
// ---------------------------------------------------------------------------
__global__ __launch_bounds__(256) void match_kernel(const char* __restrict__ d2,
                                                    const char* __restrict__ d1,
                                                    const char* __restrict__ d0,
                                                    float* __restrict__ pV1,
                                                    int* __restrict__ pI1,
                                                    float* __restrict__ pV2) {
    __shared__ __align__(16) char sAB[16384];      // sA 8KB | sB 8KB
    const int bid = blockIdx.x;                    // ((t*16)+rb)*16 + cb
    const int cb  = bid & 15;
    const int rb  = (bid >> 4) & 15;
    const int t   = bid >> 8;
    const int tid = threadIdx.x;
    const int l   = tid & 63;
    const int wr  = (tid >> 7) & 1;                // wave row quadrant
    const int wc  = (tid >> 6) & 1;                // wave col quadrant

    const char* const dsel[3] = {d2, d1, d0};
    const int adx[6] = {0, 0, 1, 1, 0, 2};
    const int bdx[6] = {0, 1, 0, 1, 2, 0};

    // staging: threads 0..127 -> A tile, 128..255 -> B tile; 64B per thread
    const int half = tid >> 7;
    const int g    = (tid & 127) >> 4;             // rowgroup within tile 0..7
    const int co   = (tid & 15) * 64;              // byte chunk within 1KB slab
    const int rg0  = half ? ((t + 1) * 128 + cb * 8) : (t * 128 + rb * 8);

    uint4 pr[4];
    auto issue = [&](int rd) {
        const int p = rd >> 2, s = rd & 3;
        const char* dig = dsel[half ? bdx[p] : adx[p]];
        const uint4* u = reinterpret_cast<const uint4*>(
            dig + ((size_t)(rg0 + g) * 4 + s) * 1024 + co);
        pr[0] = u[0]; pr[1] = u[1]; pr[2] = u[2]; pr[3] = u[3];
    };
    auto stage = [&]() {
        uint4* u = reinterpret_cast<uint4*>(sAB + half * 8192 + g * 1024 + co);
        u[0] = pr[0]; u[1] = pr[1]; u[2] = pr[2]; u[3] = pr[3];
    };

    int4v   acci[4][4];
    float4v accf[4][4];
#pragma unroll
    for (int fa = 0; fa < 4; ++fa)
#pragma unroll
        for (int fb = 0; fb < 4; ++fb) {
            acci[fa][fb] = (int4v){0, 0, 0, 0};
            accf[fa][fb] = (float4v){0.f, 0.f, 0.f, 0.f};
        }

    issue(0);
#pragma unroll 1
    for (int rd = 0; rd < 24; ++rd) {
        stage();
        __syncthreads();                           // tiles ready
        if (rd < 23) issue(rd + 1);                // loads fly under MFMA
        int4v af[4], bf[4];
#pragma unroll
        for (int f = 0; f < 4; ++f) {
            af[f] = *reinterpret_cast<const int4v*>(sAB + ((wr * 4 + f) << 10) + (l << 4));
            bf[f] = *reinterpret_cast<const int4v*>(sAB + 8192 + ((wc * 4 + f) << 10) + (l << 4));
        }
#pragma unroll
        for (int fa = 0; fa < 4; ++fa)
#pragma unroll
            for (int fb = 0; fb < 4; ++fb)
                acci[fa][fb] = __builtin_amdgcn_mfma_i32_16x16x64_i8(
                    af[fa], bf[fb], acci[fa][fb], 0, 0, 0);
        // epoch flush (register-only): exact i32 -> fp32 with power-of-2 scale
        if (rd == 3 || rd == 11 || rd == 23) {
            const float sc = (rd == 3) ? 6.103515625e-5f            // 2^-14
                           : (rd == 11) ? 4.76837158203125e-7f      // 2^-21
                                        : 3.725290298461914e-9f;    // 2^-28
#pragma unroll
            for (int fa = 0; fa < 4; ++fa)
#pragma unroll
                for (int fb = 0; fb < 4; ++fb) {
#pragma unroll
                    for (int r = 0; r < 4; ++r)
                        accf[fa][fb][r] = fmaf((float)acci[fa][fb][r], sc, accf[fa][fb][r]);
                    acci[fa][fb] = (int4v){0, 0, 0, 0};
                }
        }
        __syncthreads();                           // reads done before re-stage
    }

    // ---- epilogue: D row = wr*64+fa*16+4*(l>>4)+r, col = wc*64+fb*16+(l&15)
    float* exV1 = (float*)sAB;                     // [2][128]
    int*   exI1 = (int*)sAB + 256;
    float* exV2 = (float*)sAB + 512;
    __syncthreads();
#pragma unroll
    for (int fa = 0; fa < 4; ++fa) {
#pragma unroll
        for (int r = 0; r < 4; ++r) {
            float v1 = -3.0e38f, v2 = -3.0e38f; int i1 = 0;
#pragma unroll
            for (int fb = 0; fb < 4; ++fb) {
                float x  = accf[fa][fb][r];
                int  col = cb * 128 + wc * 64 + fb * 16 + (l & 15);
                if (x > v1) { v2 = v1; v1 = x; i1 = col; }
                else        { v2 = fmaxf(v2, x); }
            }
#pragma unroll
            for (int m = 1; m <= 8; m <<= 1) {     // 16-lane butterfly
                float ov1 = __shfl_xor(v1, m);
                int   oi1 = __shfl_xor(i1, m);
                float ov2 = __shfl_xor(v2, m);
                bool take = (ov1 > v1) || (ov1 == v1 && oi1 < i1);
                float nv2 = take ? fmaxf(ov2, v1) : fmaxf(v2, ov1);
                v1 = take ? ov1 : v1;  i1 = take ? oi1 : i1;  v2 = nv2;
            }
            if ((l & 15) == 0) {
                int rloc = wr * 64 + fa * 16 + (l >> 4) * 4 + r;
                exV1[wc * 128 + rloc] = v1;
                exI1[wc * 128 + rloc] = i1;
                exV2[wc * 128 + rloc] = v2;
            }
        }
    }
    __syncthreads();
    if (tid < 128) {
        float v1 = exV1[tid];       int i1 = exI1[tid];       float v2 = exV2[tid];
        float b1 = exV1[128 + tid]; int bi = exI1[128 + tid]; float b2 = exV2[128 + tid];
        bool take = (b1 > v1) || (b1 == v1 && bi < i1);
        float nv2 = take ? fmaxf(b2, v1) : fmaxf(v2, b1);
        if (take) { v1 = b1; i1 = bi; }
        int idx = (t * NPTS + rb * 128 + tid) * NPB + cb;
        pV1[idx] = v1; pI1[idx] = i1; pV2[idx] = nv2;
    }
}

// ---------------------------------------------------------------------------
// Kernel 3: global top-2 margin per row; near-ties -> worklist; safe rows
// commit approx best (error ~6e-5, far under output threshold).
// ---------------------------------------------------------------------------
__global__ __launch_bounds__(256) void margin_kernel(const float* __restrict__ pV1,
                                                     const int* __restrict__ pI1,
                                                     const float* __restrict__ pV2,
                                                     unsigned long long* __restrict__ best,
                                                     int* __restrict__ wl,
                                                     int* __restrict__ cnt) {
    int r = blockIdx.x * 256 + threadIdx.x;        // 0..14335
    float v1 = -3.0e38f, v2 = -3.0e38f; int i1 = 0;
#pragma unroll
    for (int cbk = 0; cbk < NPB; ++cbk) {          // ascending -> first-occurrence
        int idx = r * NPB + cbk;
        float a1 = pV1[idx]; int ai = pI1[idx]; float a2 = pV2[idx];
        if (a1 > v1) { v2 = fmaxf(v1, a2); v1 = a1; i1 = ai; }
        else         { v2 = fmaxf(v2, a1); }
    }
    if (v1 - v2 < MARGIN_THR) {
        best[r] = 0ull;
        wl[atomicAdd(cnt, 1)] = r;
    } else {
        best[r] = packVI(v1, i1);
    }
}

// ---------------------------------------------------------------------------
// Kernel 4: exact fp32 rescore of flagged rows (expected ~tens). Work item =
// (row, 256-col chunk); wave butterfly top-1; packed atomicMax merge.
// ---------------------------------------------------------------------------
__global__ __launch_bounds__(256) void recheck_kernel(const float* __restrict__ nd,
                                                      const int* __restrict__ wl,
                                                      const int* __restrict__ cnt,
                                                      unsigned long long* __restrict__ best) {
    __shared__ float sSrc[DD];
    const int nitems = (*cnt) * RCHUNK;
    const int tid = threadIdx.x;
#pragma unroll 1
    for (int item = blockIdx.x; item < nitems; item += gridDim.x) {
        const int r     = wl[item / RCHUNK];
        const int chunk = item % RCHUNK;
        const int t = r >> 11, row = r & (NPTS - 1);
        __syncthreads();
        if (tid < 64)
            reinterpret_cast<float4*>(sSrc)[tid] =
                reinterpret_cast<const float4*>(nd + ((size_t)(t * NPTS + row)) * DD)[tid];
        __syncthreads();
        const int col = chunk * 256 + tid;
        const float* dp = nd + ((size_t)((t + 1) * NPTS) + col) * DD;
        float a = 0.f;
#pragma unroll
        for (int k4 = 0; k4 < 64; ++k4) {          // sequential ascending k
            float4 s4 = reinterpret_cast<const float4*>(sSrc)[k4];
            float4 d4 = reinterpret_cast<const float4*>(dp)[k4];
            a = fmaf(s4.x, d4.x, a); a = fmaf(s4.y, d4.y, a);
            a = fmaf(s4.z, d4.z, a); a = fmaf(s4.w, d4.w, a);
        }
        float bv = a; int bi = col;
#pragma unroll
        for (int m = 1; m <= 32; m <<= 1) {        // 64-lane butterfly top-1
            float ov = __shfl_xor(bv, m);
            int   oi = __shfl_xor(bi, m);
            if (ov > bv || (ov == bv && oi < bi)) { bv = ov; bi = oi; }
        }
        if ((tid & 63) == 0)
            atomicMax(&best[r], packVI(bv, bi));
    }
}

// ---------------------------------------------------------------------------
// Kernel 5: unpack best[], gather matched points, write outputs.
// ---------------------------------------------------------------------------
__global__ __launch_bounds__(256) void final_kernel(const unsigned long long* __restrict__ best,
                                                    const float* __restrict__ pts,
                                                    float* __restrict__ out) {
    int r = blockIdx.x * 256 + threadIdx.x;
    int t = r >> 11;
    unsigned long long p = best[r];
    int idx = NPTS - 1 - (int)(p & 0xFFFFFFFFull);
    unsigned int b = (unsigned int)(p >> 32);
    b = (b & 0x80000000u) ? (b & 0x7FFFFFFFu) : ~b;
    out[(size_t)T1 * NPTS * 2 + r] = __uint_as_float(b);
    const float* q = pts + ((size_t)((t + 1) * NPTS) + idx) * 2;
    out[(size_t)r * 2 + 0] = q[0];
    out[(size_t)r * 2 + 1] = q[1];
}

// ---------------------------------------------------------------------------
extern "C" void kernel_launch(void* const* d_in, const int* in_sizes, int n_in,
                              void* d_out, int out_size, void* d_ws, size_t ws_size,
                              hipStream_t stream) {
    const float* desc = (const float*)d_in[0];     // [8, 2048, 256] fp32
    const float* pts  = (const float*)d_in[1];     // [8, 2048, 2]   fp32
    float* ws = (float*)d_ws;
    float* nd = ws + O_ND;
    char* d2 = (char*)(ws + O_D2);
    char* d1 = (char*)(ws + O_D1);
    char* d0 = (char*)(ws + O_D0);
    float* pV1 = ws + O_PV1;
    int*   pI1 = (int*)(ws + O_PI1);
    float* pV2 = ws + O_PV2;
    unsigned long long* best = (unsigned long long*)(ws + O_BEST);
    int* wl  = (int*)(ws + O_WL);
    int* cnt = (int*)(ws + O_CNT);

    prep_kernel<<<(T_ALL * NPTS) / 4, 256, 0, stream>>>(desc, nd, d2, d1, d0, cnt);
    match_kernel<<<T1 * 16 * 16, 256, 0, stream>>>(d2, d1, d0, pV1, pI1, pV2);
    margin_kernel<<<(T1 * NPTS) / 256, 256, 0, stream>>>(pV1, pI1, pV2, best, wl, cnt);
    recheck_kernel<<<2048, 256, 0, stream>>>(nd, wl, cnt, best);
    final_kernel<<<(T1 * NPTS) / 256, 256, 0, stream>>>(best, pts, (float*)d_out);
}

// Round 10
// 163.447 us; speedup vs baseline: 6.9687x; 1.6757x over previous
//
#include <hip/hip_runtime.h>

// Problem constants (fixed by setup_inputs: T=8, N=2048, D=256)
#define T_ALL 8
#define T1    7
#define NPTS  2048
#define DD    256
#define NPB   16                     // 128-col blocks per frame
#define MARGIN_THR 2.0e-4f           // 2x the 9.6e-5 rigorous (C-S) margin bound
#define RCHUNK 8                     // recheck col-chunks per row (256 cols each)

// ws layout (floats)
#define O_ND    0                                  // fp32 normalized [16384][256]
#define O_HI    (O_ND + T_ALL*NPTS*DD)             // bf16 hi, frag layout (shorts)
#define O_LO    (O_HI + T_ALL*NPTS*DD/2)
#define O_PV1   (O_LO + T_ALL*NPTS*DD/2)           // per (row, colblock) top1
#define O_PI1   (O_PV1 + T1*NPTS*NPB)
#define O_PV2   (O_PI1 + T1*NPTS*NPB)              // per (row, colblock) top2
#define O_BEST  (O_PV2 + T1*NPTS*NPB)              // u64 [14336]
#define O_WL    (O_BEST + T1*NPTS*2)               // int worklist [14336]
#define O_CNT   (O_WL + T1*NPTS)                   // int counter

typedef __attribute__((ext_vector_type(8))) short short8v;   // 8 bf16 (4 VGPR)
typedef __attribute__((ext_vector_type(4))) float float4v;   // MFMA acc

__device__ __forceinline__ unsigned short f2bf(float x) {    // RNE f32->bf16
    unsigned u = __float_as_uint(x);
    return (unsigned short)((u + 0x7FFFu + ((u >> 16) & 1u)) >> 16);
}
__device__ __forceinline__ float bf2f(unsigned short h) {
    return __uint_as_float(((unsigned)h) << 16);
}
// monotone pack: larger value wins; equal value -> smaller idx wins
__device__ __forceinline__ unsigned long long packVI(float v, int idx) {
    unsigned int b = __float_as_uint(v);
    b = (b & 0x80000000u) ? ~b : (b | 0x80000000u);
    return ((unsigned long long)b << 32) | (unsigned int)(NPTS - 1 - idx);
}

// ---------------------------------------------------------------------------
// Kernel 1: normalize rows; emit fp32 nd + bf16 hi/lo in MFMA-frag layout.
// Frag layout per 16-row group: [kstep 0..7][lane 0..63][e 0..7] shorts where
// lane=(row&15)+16*((k>>2)&3), e=4*((k>>4)&1)+(k&3), k=kstep*32+kk. A and B
// use the SAME map, so any HW k-permutation cancels in the dot product.
// Also zeroes the recheck worklist counter.
// ---------------------------------------------------------------------------
__global__ __launch_bounds__(256) void prep_kernel(const float* __restrict__ desc,
                                                   float* __restrict__ nd,
                                                   ushort* __restrict__ ghi,
                                                   ushort* __restrict__ glo,
                                                   int* __restrict__ cnt) {
    int gid  = blockIdx.x * 256 + threadIdx.x;
    if (gid == 0) *cnt = 0;
    int row  = gid >> 6;
    int lane = gid & 63;
    float4 v = reinterpret_cast<const float4*>(desc)[(size_t)row * (DD / 4) + lane];
    float s = v.x * v.x + v.y * v.y + v.z * v.z + v.w * v.w;
#pragma unroll
    for (int off = 32; off >= 1; off >>= 1) s += __shfl_xor(s, off, 64);
    float n = fmaxf(sqrtf(s), 1e-8f);
    float4 o = make_float4(v.x / n, v.y / n, v.z / n, v.w / n);
    reinterpret_cast<float4*>(nd)[(size_t)row * (DD / 4) + lane] = o;

    ushort4 h, l;
    h.x = f2bf(o.x); l.x = f2bf(o.x - bf2f(h.x));
    h.y = f2bf(o.y); l.y = f2bf(o.y - bf2f(h.y));
    h.z = f2bf(o.z); l.z = f2bf(o.z - bf2f(h.z));
    h.w = f2bf(o.w); l.w = f2bf(o.w - bf2f(h.w));
    // k = 4*lane + j: kstep=lane>>3, sub=lane&3, eb=(lane>>2)&1, e=4*eb+j
    size_t base = ((size_t)(row >> 4) * 8 + (lane >> 3)) * 512
                + (size_t)((row & 15) + 16 * (lane & 3)) * 8 + 4 * ((lane >> 2) & 1);
    *reinterpret_cast<ushort4*>(ghi + base) = h;
    *reinterpret_cast<ushort4*>(glo + base) = l;
}

// ---------------------------------------------------------------------------
// Kernel 2: bf16 MFMA match. Block = 256 thr (4 waves), tile 128x128,
// K_eff = 768 (3 passes: hi*hi, hi*lo, lo*hi), BK=32 per round, 24 rounds.
// MFMA accumulates fp32 directly -> acc state is 64 regs (R9's dual
// i32+f32 acc spilled 75 MB to scratch; this structure stayed resident in R7).
// ---------------------------------------------------------------------------
__global__ __launch_bounds__(256) void match_kernel(const ushort* __restrict__ ghi,
                                                    const ushort* __restrict__ glo,
                                                    float* __restrict__ pV1,
                                                    int* __restrict__ pI1,
                                                    float* __restrict__ pV2) {
    __shared__ __align__(16) ushort sAB[8192];     // sA 8KB | sB 8KB
    const int bid = blockIdx.x;                    // ((t*16)+rb)*16 + cb
    const int cb  = bid & 15;
    const int rb  = (bid >> 4) & 15;
    const int t   = bid >> 8;
    const int tid = threadIdx.x;
    const int w   = tid >> 6;                      // wave 0..3
    const int l   = tid & 63;
    const int wr  = w >> 1;                        // row quadrant
    const int wc  = w & 1;                         // col quadrant

    // staging role: threads 0..127 -> A, 128..255 -> B; 64B per thread/round
    const int half = tid >> 7;
    const int g    = (tid & 127) >> 4;             // row/col group 0..7
    const int c    = tid & 15;                     // 64B chunk
    const int rg   = half ? ((t + 1) * 128 + cb * 8 + g)
                          : (t * 128 + rb * 8 + g);

    uint4 pr0, pr1, pr2, pr3;
    auto issue = [&](int rd) {
        bool useLo = half ? (rd >= 8 && rd < 16) : (rd >= 16);
        const ushort* bp = useLo ? glo : ghi;
        const ushort* sp = bp + (((size_t)rg * 8 + (rd & 7)) << 9) + (c << 5);
        const uint4* u = reinterpret_cast<const uint4*>(sp);
        pr0 = u[0]; pr1 = u[1]; pr2 = u[2]; pr3 = u[3];
    };
    auto stage = [&]() {
        ushort* d = sAB + (half ? 4096 : 0) + (g << 9) + (c << 5);
        uint4* u = reinterpret_cast<uint4*>(d);
        u[0] = pr0; u[1] = pr1; u[2] = pr2; u[3] = pr3;
    };

    float4v acc[4][4];
#pragma unroll
    for (int fa = 0; fa < 4; ++fa)
#pragma unroll
        for (int fb = 0; fb < 4; ++fb) acc[fa][fb] = (float4v){0.f, 0.f, 0.f, 0.f};

    issue(0);
#pragma unroll 1
    for (int rd = 0; rd < 24; ++rd) {
        stage();
        __syncthreads();                           // tiles ready
        if (rd < 23) issue(rd + 1);                // loads fly under MFMA
        short8v af[4], bfr[4];
#pragma unroll
        for (int f = 0; f < 4; ++f) {
            af[f]  = *reinterpret_cast<const short8v*>(sAB + ((wr * 4 + f) << 9) + (l << 3));
            bfr[f] = *reinterpret_cast<const short8v*>(sAB + 4096 + ((wc * 4 + f) << 9) + (l << 3));
        }
#pragma unroll
        for (int fa = 0; fa < 4; ++fa)
#pragma unroll
            for (int fb = 0; fb < 4; ++fb)
                acc[fa][fb] = __builtin_amdgcn_mfma_f32_16x16x32_bf16(
                    af[fa], bfr[fb], acc[fa][fb], 0, 0, 0);
        __syncthreads();                           // reads done before re-stage
    }

    // ---- epilogue: D row = wr*64+fa*16+4*(l>>4)+r, col = wc*64+fb*16+(l&15)
    float* exV1 = (float*)sAB;                     // [2][128]
    int*   exI1 = (int*)sAB + 256;
    float* exV2 = (float*)sAB + 512;
    __syncthreads();
#pragma unroll
    for (int fa = 0; fa < 4; ++fa) {
#pragma unroll
        for (int r = 0; r < 4; ++r) {
            float v1 = -3.0e38f, v2 = -3.0e38f; int i1 = 0;
#pragma unroll
            for (int fb = 0; fb < 4; ++fb) {
                float x  = acc[fa][fb][r];
                int  col = cb * 128 + wc * 64 + fb * 16 + (l & 15);
                if (x > v1) { v2 = v1; v1 = x; i1 = col; }
                else        { v2 = fmaxf(v2, x); }
            }
#pragma unroll
            for (int m = 1; m <= 8; m <<= 1) {     // 16-lane butterfly
                float ov1 = __shfl_xor(v1, m);
                int   oi1 = __shfl_xor(i1, m);
                float ov2 = __shfl_xor(v2, m);
                bool take = (ov1 > v1) || (ov1 == v1 && oi1 < i1);
                float nv2 = take ? fmaxf(ov2, v1) : fmaxf(v2, ov1);
                v1 = take ? ov1 : v1;  i1 = take ? oi1 : i1;  v2 = nv2;
            }
            if ((l & 15) == 0) {
                int rloc = wr * 64 + fa * 16 + (l >> 4) * 4 + r;
                exV1[wc * 128 + rloc] = v1;
                exI1[wc * 128 + rloc] = i1;
                exV2[wc * 128 + rloc] = v2;
            }
        }
    }
    __syncthreads();
    if (tid < 128) {
        float v1 = exV1[tid];       int i1 = exI1[tid];       float v2 = exV2[tid];
        float b1 = exV1[128 + tid]; int bi = exI1[128 + tid]; float b2 = exV2[128 + tid];
        bool take = (b1 > v1) || (b1 == v1 && bi < i1);
        float nv2 = take ? fmaxf(b2, v1) : fmaxf(v2, b1);
        if (take) { v1 = b1; i1 = bi; }
        int idx = (t * NPTS + rb * 128 + tid) * NPB + cb;
        pV1[idx] = v1; pI1[idx] = i1; pV2[idx] = nv2;
    }
}

// ---------------------------------------------------------------------------
// Kernel 3: global top-2 margin per row; near-ties -> worklist; safe rows
// commit approx best (value error <= 4.8e-5 << bf16-granular 8.75e-2 bar).
// ---------------------------------------------------------------------------
__global__ __launch_bounds__(256) void margin_kernel(const float* __restrict__ pV1,
                                                     const int* __restrict__ pI1,
                                                     const float* __restrict__ pV2,
                                                     unsigned long long* __restrict__ best,
                                                     int* __restrict__ wl,
                                                     int* __restrict__ cnt) {
    int r = blockIdx.x * 256 + threadIdx.x;        // 0..14335
    float v1 = -3.0e38f, v2 = -3.0e38f; int i1 = 0;
#pragma unroll
    for (int cbk = 0; cbk < NPB; ++cbk) {          // ascending -> first-occurrence
        int idx = r * NPB + cbk;
        float a1 = pV1[idx]; int ai = pI1[idx]; float a2 = pV2[idx];
        if (a1 > v1) { v2 = fmaxf(v1, a2); v1 = a1; i1 = ai; }
        else         { v2 = fmaxf(v2, a1); }
    }
    if (v1 - v2 < MARGIN_THR) {
        best[r] = 0ull;
        wl[atomicAdd(cnt, 1)] = r;
    } else {
        best[r] = packVI(v1, i1);
    }
}

// ---------------------------------------------------------------------------
// Kernel 4: exact fp32 rescore of flagged rows (~1-2%). Work item =
// (row, 256-col chunk); wave butterfly top-1; packed atomicMax merge
// (order-independent). Same ascending-k fmaf chain as the bitwise-matching
// R2-R6 exact path.
// ---------------------------------------------------------------------------
__global__ __launch_bounds__(256) void recheck_kernel(const float* __restrict__ nd,
                                                      const int* __restrict__ wl,
                                                      const int* __restrict__ cnt,
                                                      unsigned long long* __restrict__ best) {
    __shared__ float sSrc[DD];
    const int nitems = (*cnt) * RCHUNK;
    const int tid = threadIdx.x;
#pragma unroll 1
    for (int item = blockIdx.x; item < nitems; item += gridDim.x) {
        const int r     = wl[item / RCHUNK];
        const int chunk = item % RCHUNK;
        const int t = r >> 11, row = r & (NPTS - 1);
        __syncthreads();
        if (tid < 64)
            reinterpret_cast<float4*>(sSrc)[tid] =
                reinterpret_cast<const float4*>(nd + ((size_t)(t * NPTS + row)) * DD)[tid];
        __syncthreads();
        const int col = chunk * 256 + tid;
        const float* dp = nd + ((size_t)((t + 1) * NPTS) + col) * DD;
        float a = 0.f;
#pragma unroll
        for (int k4 = 0; k4 < 64; ++k4) {          // sequential ascending k
            float4 s4 = reinterpret_cast<const float4*>(sSrc)[k4];
            float4 d4 = reinterpret_cast<const float4*>(dp)[k4];
            a = fmaf(s4.x, d4.x, a); a = fmaf(s4.y, d4.y, a);
            a = fmaf(s4.z, d4.z, a); a = fmaf(s4.w, d4.w, a);
        }
        float bv = a; int bi = col;
#pragma unroll
        for (int m = 1; m <= 32; m <<= 1) {        // 64-lane butterfly top-1
            float ov = __shfl_xor(bv, m);
            int   oi = __shfl_xor(bi, m);
            if (ov > bv || (ov == bv && oi < bi)) { bv = ov; bi = oi; }
        }
        if ((tid & 63) == 0)
            atomicMax(&best[r], packVI(bv, bi));
    }
}

// ---------------------------------------------------------------------------
// Kernel 5: unpack best[], gather matched points, write outputs.
// ---------------------------------------------------------------------------
__global__ __launch_bounds__(256) void final_kernel(const unsigned long long* __restrict__ best,
                                                    const float* __restrict__ pts,
                                                    float* __restrict__ out) {
    int r = blockIdx.x * 256 + threadIdx.x;
    int t = r >> 11;
    unsigned long long p = best[r];
    int idx = NPTS - 1 - (int)(p & 0xFFFFFFFFull);
    unsigned int b = (unsigned int)(p >> 32);
    b = (b & 0x80000000u) ? (b & 0x7FFFFFFFu) : ~b;
    out[(size_t)T1 * NPTS * 2 + r] = __uint_as_float(b);
    const float* q = pts + ((size_t)((t + 1) * NPTS) + idx) * 2;
    out[(size_t)r * 2 + 0] = q[0];
    out[(size_t)r * 2 + 1] = q[1];
}

// ---------------------------------------------------------------------------
extern "C" void kernel_launch(void* const* d_in, const int* in_sizes, int n_in,
                              void* d_out, int out_size, void* d_ws, size_t ws_size,
                              hipStream_t stream) {
    const float* desc = (const float*)d_in[0];     // [8, 2048, 256] fp32
    const float* pts  = (const float*)d_in[1];     // [8, 2048, 2]   fp32
    float* ws = (float*)d_ws;
    float* nd  = ws + O_ND;
    ushort* ghi = (ushort*)(ws + O_HI);
    ushort* glo = (ushort*)(ws + O_LO);
    float* pV1 = ws + O_PV1;
    int*   pI1 = (int*)(ws + O_PI1);
    float* pV2 = ws + O_PV2;
    unsigned long long* best = (unsigned long long*)(ws + O_BEST);
    int* wl  = (int*)(ws + O_WL);
    int* cnt = (int*)(ws + O_CNT);

    prep_kernel<<<(T_ALL * NPTS) / 4, 256, 0, stream>>>(desc, nd, ghi, glo, cnt);
    match_kernel<<<T1 * 16 * 16, 256, 0, stream>>>(ghi, glo, pV1, pI1, pV2);
    margin_kernel<<<(T1 * NPTS) / 256, 256, 0, stream>>>(pV1, pI1, pV2, best, wl, cnt);
    recheck_kernel<<<2048, 256, 0, stream>>>(nd, wl, cnt, best);
    final_kernel<<<(T1 * NPTS) / 256, 256, 0, stream>>>(best, pts, (float*)d_out);
}